// Round 1
// baseline (82.363 us; speedup 1.0000x reference)
//
#include <hip/hip_runtime.h>
#include <math.h>

#define NFEAT 12
#define NMASK 4095          // 2^12 - 1
#define BATCH 4096

// ---------------------------------------------------------------------------
// Kernel 1: build FM lookup table (4096 floats) from ie_vars via lattice DP.
//   g[m-1] for mask m in [1, 4095]:
//     pop==1 : g = |v|
//     pop 2..11 : g = max over children g[m - lowbit] + |v[m-1]|
//     m == 4095 (full) : g = 1.0
//   FM_table[A] = (A==0) ? 0 : min(g[A-1], 1)
// ---------------------------------------------------------------------------
__global__ void build_fm_kernel(const float* __restrict__ ie,
                                float* __restrict__ fm_table) {
    __shared__ float g[NMASK];

    // level 1 (popcount == 1)
    for (int m = 1 + (int)threadIdx.x; m <= NMASK; m += (int)blockDim.x) {
        if (__popc(m) == 1) g[m - 1] = fabsf(ie[m - 1]);
    }
    __syncthreads();

    // levels 2 .. N-1
    for (int k = 2; k <= NFEAT - 1; ++k) {
        for (int m = 1 + (int)threadIdx.x; m <= NMASK; m += (int)blockDim.x) {
            if (__popc(m) == k) {
                float best = -INFINITY;
                int mm = m;
                while (mm) {
                    int low = mm & (-mm);
                    best = fmaxf(best, g[(m - low) - 1]);
                    mm -= low;
                }
                g[m - 1] = best + fabsf(ie[m - 1]);
            }
        }
        __syncthreads();
    }

    if (threadIdx.x == 0) g[NMASK - 1] = 1.0f;   // full mask
    __syncthreads();

    for (int a = (int)threadIdx.x; a < NMASK + 1; a += (int)blockDim.x) {
        fm_table[a] = (a == 0) ? 0.0f : fminf(g[a - 1], 1.0f);
    }
}

// ---------------------------------------------------------------------------
// Kernel 2: one wave (64 lanes) per batch row.
//   f(y) = sum_{A=0..4095} FM[A] * prod_{i in A} y_i * prod_{i notin A} (1-y_i)
//   A = (t<<6) | lane. Lane holds tlo (bits 0..5 = lane) and thi for hi=lane;
//   broadcast thi via shuffle, FMA vs LDS (lane-contiguous -> conflict free).
//   left[row] = min(f(l), f(u)); right[row] = f(u).
// ---------------------------------------------------------------------------
__global__ __launch_bounds__(256) void eval_kernel(const float* __restrict__ x,
                                                   const float* __restrict__ fm_table,
                                                   float* __restrict__ out) {
    __shared__ float FM[NMASK + 1];
    for (int i = (int)threadIdx.x; i < NMASK + 1; i += (int)blockDim.x)
        FM[i] = fm_table[i];
    __syncthreads();

    const int wave = (int)threadIdx.x >> 6;   // 4 waves per block
    const int lane = (int)threadIdx.x & 63;
    const int row  = (int)blockIdx.x * 4 + wave;
    if (row >= BATCH) return;

    const float* xr = x + row * (2 * NFEAT);

    float res[2];
#pragma unroll
    for (int s = 0; s < 2; ++s) {
        const float* y = xr + s * NFEAT;   // s=0: lower bounds, s=1: upper

        float tlo = 1.0f;
#pragma unroll
        for (int i = 0; i < 6; ++i) {
            float yi = y[i];
            tlo *= ((lane >> i) & 1) ? yi : (1.0f - yi);
        }
        float thi = 1.0f;
#pragma unroll
        for (int i = 0; i < 6; ++i) {
            float yi = y[6 + i];
            thi *= ((lane >> i) & 1) ? yi : (1.0f - yi);
        }

        float acc = 0.0f;
#pragma unroll
        for (int t = 0; t < 64; ++t) {
            float th = __shfl(thi, t, 64);
            acc = fmaf(FM[t * 64 + lane] * th, tlo, acc);
        }

        // 64-lane butterfly reduce
#pragma unroll
        for (int off = 32; off >= 1; off >>= 1)
            acc += __shfl_xor(acc, off, 64);

        res[s] = acc;
    }

    if (lane == 0) {
        out[row]         = fminf(res[0], res[1]);  // left  = min(f(l), f(u))
        out[BATCH + row] = res[1];                 // right = f(u)
    }
}

extern "C" void kernel_launch(void* const* d_in, const int* in_sizes, int n_in,
                              void* d_out, int out_size, void* d_ws, size_t ws_size,
                              hipStream_t stream) {
    const float* x   = (const float*)d_in[0];   // (4096, 24)
    const float* ie  = (const float*)d_in[1];   // (4094, 1)
    // d_in[2] = feature_matrix — provably unused (Mobius identity)
    float* out = (float*)d_out;                 // left(4096) ++ right(4096)
    float* fm  = (float*)d_ws;                  // 4096 floats scratch

    build_fm_kernel<<<1, 256, 0, stream>>>(ie, fm);
    eval_kernel<<<BATCH / 4, 256, 0, stream>>>(x, fm, out);
}

// Round 2
// 43.267 us; speedup vs baseline: 1.9036x; 1.9036x over previous
//
#include <hip/hip_runtime.h>
#include <math.h>

#define NFEAT 12
#define NMASK 4095          // 2^12 - 1
#define BATCH 4096

// ---------------------------------------------------------------------------
// Kernel 1: build FM lookup table (4096 floats) from ie_vars via lattice DP.
//   g[m] (mask m in [1,4095], g indexed by mask):
//     pop==1 : g = |v[m]|
//     pop 2..11 : g = max over children g[m ^ lowbit] + |v[m]|
//     m == 4095 : g = 1.0
//   fm_table[A] = (A==0) ? 0 : min(g[A], 1)
// Latency-optimized: 12 independent LDS child loads per mask (no dependent
// chain), ie pre-staged in LDS, 1024 threads.
// ---------------------------------------------------------------------------
__global__ __launch_bounds__(1024) void build_fm_kernel(const float* __restrict__ ie,
                                                        float* __restrict__ fm_table) {
    __shared__ float g[NMASK + 1];    // indexed by mask; g[0] unused
    __shared__ float va[NMASK + 1];   // |ie| indexed by mask (m=1..4094)

    const int tid = (int)threadIdx.x;

    // stage |ie| into LDS (ie has 4094 entries for masks 1..4094)
    for (int m = 1 + tid; m <= NMASK - 1; m += 1024)
        va[m] = fabsf(ie[m - 1]);

    // level 1 (popcount == 1): g[1<<i] = |v|
    if (tid < NFEAT) {
        int m = 1 << tid;
        g[m] = fabsf(ie[m - 1]);
    }
    __syncthreads();

    // levels 2 .. 11: reads only level k-1, writes only level k -> no hazard
    for (int k = 2; k <= NFEAT - 1; ++k) {
        for (int m = 1 + tid; m <= NMASK; m += 1024) {
            if (__popc(m) == k) {
                float best = -INFINITY;
#pragma unroll
                for (int i = 0; i < NFEAT; ++i) {
                    const int has = (m >> i) & 1;
                    const int idx = m ^ (has << i);   // child if bit set, else m
                    const float c = g[idx];           // independent load
                    best = has ? fmaxf(best, c) : best;
                }
                g[m] = best + va[m];
            }
        }
        __syncthreads();
    }

    if (tid == 0) g[NMASK] = 1.0f;    // full mask
    __syncthreads();

    for (int a = tid; a <= NMASK; a += 1024)
        fm_table[a] = (a == 0) ? 0.0f : fminf(g[a], 1.0f);
}

// ---------------------------------------------------------------------------
// Kernel 2: one wave (64 lanes) per batch row.
//   f(y) = sum_{A=0..4095} FM[A] * prod_{i in A} y_i * prod_{i notin A} (1-y_i)
//   A = (t<<6) | lane. Lane holds tlo (bits 0..5 = lane) and thi for hi=lane;
//   broadcast thi via shuffle, FMA vs LDS (lane-contiguous -> conflict free).
//   left[row] = min(f(l), f(u)); right[row] = f(u).
// ---------------------------------------------------------------------------
__global__ __launch_bounds__(256) void eval_kernel(const float* __restrict__ x,
                                                   const float* __restrict__ fm_table,
                                                   float* __restrict__ out) {
    __shared__ float FM[NMASK + 1];
    for (int i = (int)threadIdx.x; i < NMASK + 1; i += (int)blockDim.x)
        FM[i] = fm_table[i];
    __syncthreads();

    const int wave = (int)threadIdx.x >> 6;   // 4 waves per block
    const int lane = (int)threadIdx.x & 63;
    const int row  = (int)blockIdx.x * 4 + wave;
    if (row >= BATCH) return;

    const float* xr = x + row * (2 * NFEAT);

    float res[2];
#pragma unroll
    for (int s = 0; s < 2; ++s) {
        const float* y = xr + s * NFEAT;   // s=0: lower bounds, s=1: upper

        float tlo = 1.0f;
#pragma unroll
        for (int i = 0; i < 6; ++i) {
            float yi = y[i];
            tlo *= ((lane >> i) & 1) ? yi : (1.0f - yi);
        }
        float thi = 1.0f;
#pragma unroll
        for (int i = 0; i < 6; ++i) {
            float yi = y[6 + i];
            thi *= ((lane >> i) & 1) ? yi : (1.0f - yi);
        }

        float acc = 0.0f;
#pragma unroll
        for (int t = 0; t < 64; ++t) {
            float th = __shfl(thi, t, 64);
            acc = fmaf(FM[t * 64 + lane] * th, tlo, acc);
        }

        // 64-lane butterfly reduce
#pragma unroll
        for (int off = 32; off >= 1; off >>= 1)
            acc += __shfl_xor(acc, off, 64);

        res[s] = acc;
    }

    if (lane == 0) {
        out[row]         = fminf(res[0], res[1]);  // left  = min(f(l), f(u))
        out[BATCH + row] = res[1];                 // right = f(u)
    }
}

extern "C" void kernel_launch(void* const* d_in, const int* in_sizes, int n_in,
                              void* d_out, int out_size, void* d_ws, size_t ws_size,
                              hipStream_t stream) {
    const float* x   = (const float*)d_in[0];   // (4096, 24)
    const float* ie  = (const float*)d_in[1];   // (4094, 1)
    // d_in[2] = feature_matrix — provably unused (Mobius identity)
    float* out = (float*)d_out;                 // left(4096) ++ right(4096)
    float* fm  = (float*)d_ws;                  // 4096 floats scratch

    build_fm_kernel<<<1, 1024, 0, stream>>>(ie, fm);
    eval_kernel<<<BATCH / 4, 256, 0, stream>>>(x, fm, out);
}

// Round 3
// 26.918 us; speedup vs baseline: 3.0598x; 1.6074x over previous
//
#include <hip/hip_runtime.h>
#include <math.h>

#define NFEAT 12
#define NMASK 4095          // 2^12 - 1
#define BATCH 4096

// Binomial table C(b, j) for bit positions b=0..11, j=0..12 (colex rank).
__device__ const short C_TBL[12][13] = {
    {1, 0, 0,  0,  0,  0,  0,  0,  0,  0,  0, 0, 0},
    {1, 1, 0,  0,  0,  0,  0,  0,  0,  0,  0, 0, 0},
    {1, 2, 1,  0,  0,  0,  0,  0,  0,  0,  0, 0, 0},
    {1, 3, 3,  1,  0,  0,  0,  0,  0,  0,  0, 0, 0},
    {1, 4, 6,  4,  1,  0,  0,  0,  0,  0,  0, 0, 0},
    {1, 5, 10, 10, 5,  1,  0,  0,  0,  0,  0, 0, 0},
    {1, 6, 15, 20, 15, 6,  1,  0,  0,  0,  0, 0, 0},
    {1, 7, 21, 35, 35, 21, 7,  1,  0,  0,  0, 0, 0},
    {1, 8, 28, 56, 70, 56, 28, 8,  1,  0,  0, 0, 0},
    {1, 9, 36, 84, 126,126,84, 36, 9,  1,  0, 0, 0},
    {1,10, 45,120,210,252,210,120,45, 10,  1, 0, 0},
    {1,11, 55,165,330,462,462,330,165,55, 11, 1, 0},
};
// Start offset of popcount-level k in the packed (popcount-sorted) order.
__device__ const short LVL_OFF[13] = {0,0,12,78,298,793,1585,2509,3301,3796,4016,4082,4094};
__device__ const short LVL_SZ[13]  = {0,12,66,220,495,792,924,792,495,220,66,12,1};

// ---------------------------------------------------------------------------
// Kernel 1: FM lookup table from ie_vars via lattice DP, popcount-sorted.
// Each level k processes only its C(12,k) live masks (max 924 < 1024 thr)
// in ONE iteration: 10x less LDS traffic than the predicate-all-masks loop.
// ---------------------------------------------------------------------------
__global__ __launch_bounds__(1024) void build_fm_kernel(const float* __restrict__ ie,
                                                        float* __restrict__ fm_table) {
    __shared__ float g[NMASK + 1];     // DP value, indexed by mask
    __shared__ float va[NMASK + 1];    // |ie|, indexed by mask
    __shared__ short perm[NMASK + 1];  // popcount-sorted rank -> mask

    const int tid = (int)threadIdx.x;

    // Phase A: stage |ie|, seed level 1, build the rank permutation.
    for (int m = 1 + tid; m <= NMASK; m += 1024) {
        const float v = (m <= NMASK - 1) ? fabsf(ie[m - 1]) : 0.0f;
        va[m] = v;
        const int p = __popc(m);
        int rank = 0, mm = m, j = 0;          // colex rank within level p
        while (mm) {
            const int b = __ffs(mm) - 1;
            ++j;
            rank += C_TBL[b][j];
            mm &= mm - 1;
        }
        perm[LVL_OFF[p] + rank] = (short)m;
        if (p == 1) g[m] = v;
    }
    __syncthreads();

    // Phase B: levels 2..11 — one iteration each, only live masks touched.
    for (int k = 2; k <= NFEAT - 1; ++k) {
        if (tid < LVL_SZ[k]) {
            const int m = perm[LVL_OFF[k] + tid];
            float best = -INFINITY;
#pragma unroll
            for (int i = 0; i < NFEAT; ++i) {
                const int has = (m >> i) & 1;
                const float c = g[m ^ (has << i)];   // child if bit set (independent loads)
                best = has ? fmaxf(best, c) : best;
            }
            g[m] = best + va[m];
        }
        __syncthreads();
    }

    if (tid == 0) g[NMASK] = 1.0f;   // full mask
    __syncthreads();

    for (int a = tid; a <= NMASK; a += 1024)
        fm_table[a] = (a == 0) ? 0.0f : fminf(g[a], 1.0f);
}

// ---------------------------------------------------------------------------
// Kernel 2: f(y) = sum_A FM[A] * prod_{i in A} y_i * prod_{i notin A} (1-y_i)
// Factorized: f = sum_l tlo[l] * ( sum_t thi[t] * FM[t*64+l] ).
// One wave handles 4 rows (8 evals). Per t: 1 ds_read (shared by all 8) +
// 8 readlane broadcasts (SALU, off the LDS pipe) + 8 FMA. tlo multiplies once.
// ---------------------------------------------------------------------------
__device__ __forceinline__ float bcast(float v, int t) {
#if __has_builtin(__builtin_amdgcn_readlane)
    return __int_as_float(__builtin_amdgcn_readlane(__float_as_int(v), t));
#else
    return __shfl(v, t, 64);
#endif
}

__global__ __launch_bounds__(256) void eval_kernel(const float* __restrict__ x,
                                                   const float* __restrict__ fm_table,
                                                   float* __restrict__ out) {
    __shared__ float FM[NMASK + 1];
    {
        const float4* s4 = (const float4*)fm_table;
        float4* d4 = (float4*)FM;
        for (int i = (int)threadIdx.x; i < (NMASK + 1) / 4; i += 256) d4[i] = s4[i];
    }
    __syncthreads();

    const int lane = (int)threadIdx.x & 63;
    const int wave = (int)threadIdx.x >> 6;
    const int row0 = (int)blockIdx.x * 16 + wave * 4;   // 4 rows per wave

    float tlo[8], thi[8], w[8];   // e = r*2 + s  (s=0: lower, s=1: upper)
#pragma unroll
    for (int e = 0; e < 8; ++e) {
        const int r = e >> 1, s = e & 1;
        const float* y = x + (row0 + r) * (2 * NFEAT) + s * NFEAT;
        float a = 1.0f, b = 1.0f;
#pragma unroll
        for (int i = 0; i < 6; ++i) {
            const float yl = y[i], yh = y[6 + i];
            a *= ((lane >> i) & 1) ? yl : 1.0f - yl;
            b *= ((lane >> i) & 1) ? yh : 1.0f - yh;
        }
        tlo[e] = a; thi[e] = b; w[e] = 0.0f;
    }

#pragma unroll
    for (int t = 0; t < 64; ++t) {
        const float fmv = FM[t * 64 + lane];   // consecutive across lanes: conflict-free
#pragma unroll
        for (int e = 0; e < 8; ++e)
            w[e] = fmaf(bcast(thi[e], t), fmv, w[e]);
    }

    float f[8];
#pragma unroll
    for (int e = 0; e < 8; ++e) {
        float v = w[e] * tlo[e];
#pragma unroll
        for (int off = 32; off >= 1; off >>= 1)
            v += __shfl_xor(v, off, 64);
        f[e] = v;
    }

    if (lane == 0) {
#pragma unroll
        for (int r = 0; r < 4; ++r) {
            const int row = row0 + r;
            out[row]         = fminf(f[2 * r], f[2 * r + 1]);  // left = min(f(l), f(u))
            out[BATCH + row] = f[2 * r + 1];                   // right = f(u)
        }
    }
}

extern "C" void kernel_launch(void* const* d_in, const int* in_sizes, int n_in,
                              void* d_out, int out_size, void* d_ws, size_t ws_size,
                              hipStream_t stream) {
    const float* x   = (const float*)d_in[0];   // (4096, 24)
    const float* ie  = (const float*)d_in[1];   // (4094, 1)
    // d_in[2] = feature_matrix — provably unused (Mobius identity)
    float* out = (float*)d_out;                 // left(4096) ++ right(4096)
    float* fm  = (float*)d_ws;                  // 4096 floats scratch

    build_fm_kernel<<<1, 1024, 0, stream>>>(ie, fm);
    eval_kernel<<<BATCH / 16, 256, 0, stream>>>(x, fm, out);
}

// Round 4
// 21.035 us; speedup vs baseline: 3.9155x; 1.2797x over previous
//
#include <hip/hip_runtime.h>
#include <math.h>

#define NFEAT 12
#define NMASK 4095          // 2^12 - 1
#define BATCH 4096
#define THREADS 512
#define ROWS_PER_BLOCK 16   // 8 waves x 2 rows/wave
#define NBLOCKS (BATCH / ROWS_PER_BLOCK)   // 256

// ---------------------------------------------------------------------------
// Compile-time popcount-sorted permutation of masks 1..4095.
// perm[LVL_OFF[k] + r] = r-th mask with popcount k. Input-independent, so
// it is baked into the binary — no runtime rank computation at all.
// ---------------------------------------------------------------------------
struct Tables { unsigned short perm[4096]; };

constexpr int cpop(int x) { int c = 0; while (x) { c += x & 1; x >>= 1; } return c; }

constexpr Tables make_tables() {
    Tables t{};
    int cnt[13] = {};
    for (int m = 1; m <= NMASK; ++m) cnt[cpop(m)]++;
    int cur[13]; int acc = 0;
    for (int k = 0; k <= 12; ++k) { cur[k] = acc; acc += cnt[k]; }
    for (int m = 1; m <= NMASK; ++m) t.perm[cur[cpop(m)]++] = (unsigned short)m;
    t.perm[4095] = 0;
    return t;
}

constexpr Tables HOST_TBL = make_tables();
__device__ const Tables TBL = HOST_TBL;   // static (constexpr) init, 8 KB

// start index of popcount-k masks in the sorted order (k = 1..12), +sentinel
__host__ __device__ constexpr int LVL_OFF_C[14] =
    {0, 0, 12, 78, 298, 793, 1585, 2509, 3301, 3796, 4016, 4082, 4094, 4095};

__device__ __forceinline__ float bcast(float v, int t) {
#if __has_builtin(__builtin_amdgcn_readlane)
    return __int_as_float(__builtin_amdgcn_readlane(__float_as_int(v), t));
#else
    return __shfl(v, t, 64);
#endif
}

// ---------------------------------------------------------------------------
// Fused kernel: each block redundantly builds the FM table in its own LDS
// (lattice DP, compile-time level schedule), then evaluates 16 batch rows:
//   f(y) = sum_A FM[A] * prod_{i in A} y_i * prod_{i notin A} (1-y_i)
//        = sum_l tlo[l] * ( sum_t thi[t] * FM[t*64+l] )       (A=(t<<6)|l)
//   left = min(f(lo), f(hi)); right = f(hi).
// ---------------------------------------------------------------------------
__global__ __launch_bounds__(THREADS) void fused_kernel(const float* __restrict__ x,
                                                        const float* __restrict__ ie,
                                                        float* __restrict__ out) {
    __shared__ float g[4096];               // DP value / FM table, by mask
    __shared__ float va[4096];              // |ie|, by mask
    __shared__ unsigned short perm[4096];

    const int tid  = (int)threadIdx.x;
    const int lane = tid & 63;
    const int wave = tid >> 6;
    const int row0 = (int)blockIdx.x * ROWS_PER_BLOCK + wave * 2;

    // ---- stage phase (no barriers yet): va, perm, level-1 seed, g[4095],
    //      and the per-lane row products tlo/thi (hides global latency) ----
#pragma unroll
    for (int i = 0; i < 4096 / THREADS; ++i) {          // 8 iterations
        const int m = tid + i * THREADS;
        perm[m] = TBL.perm[m];
        if (m >= 1 && m <= NMASK - 1) va[m] = fabsf(ie[m - 1]);
    }
    if (tid < NFEAT) { const int m = 1 << tid; g[m] = fabsf(ie[m - 1]); }
    if (tid == NFEAT) g[NMASK] = 1.0f;                  // full mask: fixed 1.0

    float tlo[4], thi[4], w[4];                         // e = r*2 + s
#pragma unroll
    for (int e = 0; e < 4; ++e) {
        const int r = e >> 1, s = e & 1;
        const float* y = x + (size_t)(row0 + r) * (2 * NFEAT) + s * NFEAT;
        float a = 1.0f, b = 1.0f;
#pragma unroll
        for (int i = 0; i < 6; ++i) {
            const float yl = y[i], yh = y[6 + i];
            a *= ((lane >> i) & 1) ? yl : 1.0f - yl;
            b *= ((lane >> i) & 1) ? yh : 1.0f - yh;
        }
        tlo[e] = a; thi[e] = b; w[e] = 0.0f;
    }
    __syncthreads();

    // ---- DP levels 2..11: compile-time schedule, only live masks touched ----
#pragma unroll
    for (int k = 2; k <= 11; ++k) {
        const int off = LVL_OFF_C[k];
        const int sz  = LVL_OFF_C[k + 1] - off;
#pragma unroll
        for (int it = 0; it < (sz + THREADS - 1) / THREADS; ++it) {
            const int idx = it * THREADS + tid;
            if (idx < sz) {
                const int m = perm[off + idx];
                float best = -INFINITY;
#pragma unroll
                for (int i = 0; i < NFEAT; ++i) {
                    const int has = (m >> i) & 1;
                    const float c = g[m ^ (has << i)]; // child if bit set; 12 independent loads
                    best = has ? fmaxf(best, c) : best;
                }
                g[m] = best + va[m];
            }
        }
        __syncthreads();
    }

    // ---- in-place clamp: FM[a] = (a==0) ? 0 : min(g[a], 1) ----
#pragma unroll
    for (int i = 0; i < 4096 / THREADS; ++i) {
        const int a = tid + i * THREADS;
        g[a] = (a == 0) ? 0.0f : fminf(g[a], 1.0f);
    }
    __syncthreads();

    // ---- eval: per t, 1 conflict-free ds_read + 4 readlane + 4 FMA ----
#pragma unroll
    for (int t = 0; t < 64; ++t) {
        const float fmv = g[t * 64 + lane];
#pragma unroll
        for (int e = 0; e < 4; ++e)
            w[e] = fmaf(bcast(thi[e], t), fmv, w[e]);
    }

    float f[4];
#pragma unroll
    for (int e = 0; e < 4; ++e) {
        float v = w[e] * tlo[e];
#pragma unroll
        for (int o = 32; o >= 1; o >>= 1)
            v += __shfl_xor(v, o, 64);
        f[e] = v;
    }

    if (lane == 0) {
#pragma unroll
        for (int r = 0; r < 2; ++r) {
            const int row = row0 + r;
            out[row]         = fminf(f[2 * r], f[2 * r + 1]);  // left = min(f(l), f(u))
            out[BATCH + row] = f[2 * r + 1];                   // right = f(u)
        }
    }
}

extern "C" void kernel_launch(void* const* d_in, const int* in_sizes, int n_in,
                              void* d_out, int out_size, void* d_ws, size_t ws_size,
                              hipStream_t stream) {
    const float* x  = (const float*)d_in[0];   // (4096, 24)
    const float* ie = (const float*)d_in[1];   // (4094, 1)
    // d_in[2] = feature_matrix — provably unused (Mobius identity)
    float* out = (float*)d_out;                // left(4096) ++ right(4096)

    fused_kernel<<<NBLOCKS, THREADS, 0, stream>>>(x, ie, out);
}

// Round 5
// 19.886 us; speedup vs baseline: 4.1417x; 1.0578x over previous
//
#include <hip/hip_runtime.h>
#include <math.h>

#define NFEAT 12
#define NMASK 4095          // 2^12 - 1
#define BATCH 4096
#define THREADS 512
#define ROWS_PER_BLOCK 16   // 8 waves x 2 rows/wave
#define NBLOCKS (BATCH / ROWS_PER_BLOCK)   // 256

// ---------------------------------------------------------------------------
// Compile-time popcount-sorted permutation of masks 1..4095 (colex within
// level irrelevant — any order works). Baked into the binary.
// ---------------------------------------------------------------------------
struct Tables { unsigned short perm[4096]; };

constexpr int cpop(int x) { int c = 0; while (x) { c += x & 1; x >>= 1; } return c; }

constexpr Tables make_tables() {
    Tables t{};
    int cnt[13] = {};
    for (int m = 1; m <= NMASK; ++m) cnt[cpop(m)]++;
    int cur[13]; int acc = 0;
    for (int k = 0; k <= 12; ++k) { cur[k] = acc; acc += cnt[k]; }
    for (int m = 1; m <= NMASK; ++m) t.perm[cur[cpop(m)]++] = (unsigned short)m;
    t.perm[4095] = 0;
    return t;
}

constexpr Tables HOST_TBL = make_tables();
__device__ const Tables TBL = HOST_TBL;   // 8 KB, L2-hot across all blocks

// DP slot schedule (compile-time). Levels 2..11 split into <=512-thread slots:
// k:   2    3    4    5    5    6    6    7    7    8    9   10   11
#define NSLOT 13
__host__ __device__ constexpr int SLOT_OFF[NSLOT] =
    {12, 78, 298, 793, 1305, 1585, 2097, 2509, 3021, 3301, 3796, 4016, 4082};
__host__ __device__ constexpr int SLOT_CNT[NSLOT] =
    {66, 220, 495, 512, 280, 512, 412, 512, 280, 495, 220, 66, 12};
// barrier after slot s iff the next slot starts a new level (and before eval)
__host__ __device__ constexpr int SLOT_BAR[NSLOT] =
    {1, 1, 1, 0, 1, 0, 1, 0, 1, 1, 1, 1, 1};

__device__ __forceinline__ float bcast(float v, int t) {
#if __has_builtin(__builtin_amdgcn_readlane)
    return __int_as_float(__builtin_amdgcn_readlane(__float_as_int(v), t));
#else
    return __shfl(v, t, 64);
#endif
}

// ---------------------------------------------------------------------------
// Fused kernel: each block builds the FM table in its own 16 KB LDS via the
// lattice DP (software-pipelined perm/ie prefetch, no LDS staging), then
// evaluates 16 batch rows:
//   f(y) = sum_A FM[A] * prod_{i in A} y_i * prod_{i notin A} (1-y_i)
//        = sum_l tlo[l] * ( sum_t thi[t] * min(g[t*64+l],1) )    (A=(t<<6)|l)
//   left = min(f(lo), f(hi)); right = f(hi).
// ---------------------------------------------------------------------------
__global__ __launch_bounds__(THREADS) void fused_kernel(const float* __restrict__ x,
                                                        const float* __restrict__ ie,
                                                        float* __restrict__ out) {
    __shared__ float g[4096];            // DP value by mask (g[0]=0, g[4095]=1)

    const int tid  = (int)threadIdx.x;
    const int lane = tid & 63;
    const int wave = tid >> 6;
    const int row0 = (int)blockIdx.x * ROWS_PER_BLOCK + wave * 2;
    const unsigned short* __restrict__ P = TBL.perm;

    // ---- prologue: prefetch perm for slots 0,1 (issue ASAP) ----
    int mA = P[SLOT_OFF[0] + (tid < SLOT_CNT[0] ? tid : 0)];
    int mB = P[SLOT_OFF[1] + (tid < SLOT_CNT[1] ? tid : 0)];

    // seeds: level 1, full mask, empty mask
    if (tid < NFEAT)            g[1 << tid] = fabsf(ie[(1 << tid) - 1]);
    else if (tid == NFEAT)      g[NMASK] = 1.0f;
    else if (tid == NFEAT + 1)  g[0] = 0.0f;

    // per-lane row products (hides x-load latency under prefetches)
    float tlo[4], thi[4], w[4];          // e = r*2 + s  (s=0: lower, s=1: upper)
#pragma unroll
    for (int e = 0; e < 4; ++e) {
        const int r = e >> 1, s = e & 1;
        const float* y = x + (size_t)(row0 + r) * (2 * NFEAT) + s * NFEAT;
        float a = 1.0f, b = 1.0f;
#pragma unroll
        for (int i = 0; i < 6; ++i) {
            const float yl = y[i], yh = y[6 + i];
            a *= ((lane >> i) & 1) ? yl : 1.0f - yl;
            b *= ((lane >> i) & 1) ? yh : 1.0f - yh;
        }
        tlo[e] = a; thi[e] = b; w[e] = 0.0f;
    }

    // ie value for slot 0 (dependent on mA; latency hidden by the code above)
    float vaA = fabsf(ie[mA - 1]);

    __syncthreads();                     // seeds visible

    // ---- DP: 13 slots, 2-deep prefetch pipeline, barriers at level edges ----
#pragma unroll
    for (int s = 0; s < NSLOT; ++s) {
        int mC = 0; float vaB = 0.0f;
        if (s + 2 < NSLOT) mC  = P[SLOT_OFF[s + 2] + (tid < SLOT_CNT[s + 2] ? tid : 0)];
        if (s + 1 < NSLOT) vaB = fabsf(ie[mB - 1]);   // perm arrived a slot ago
        if (tid < SLOT_CNT[s]) {
            const int m = mA;
            float best = -INFINITY;
#pragma unroll
            for (int i = 0; i < NFEAT; ++i) {
                const int has = (m >> i) & 1;
                const float c = g[m ^ (has << i)];   // child if bit set; 12 independent loads
                best = has ? fmaxf(best, c) : best;
            }
            g[m] = best + vaA;
        }
        if (SLOT_BAR[s]) __syncthreads();
        mA = mB; vaA = vaB; mB = mC;
    }

    // ---- eval: clamp fused into the read; 1 ds_read + 4 readlane + 4 FMA / t ----
#pragma unroll
    for (int t = 0; t < 64; ++t) {
        const float fmv = fminf(g[t * 64 + lane], 1.0f);   // conflict-free
#pragma unroll
        for (int e = 0; e < 4; ++e)
            w[e] = fmaf(bcast(thi[e], t), fmv, w[e]);
    }

    float f[4];
#pragma unroll
    for (int e = 0; e < 4; ++e) {
        float v = w[e] * tlo[e];
#pragma unroll
        for (int o = 32; o >= 1; o >>= 1)
            v += __shfl_xor(v, o, 64);
        f[e] = v;
    }

    if (lane == 0) {
#pragma unroll
        for (int r = 0; r < 2; ++r) {
            const int row = row0 + r;
            out[row]         = fminf(f[2 * r], f[2 * r + 1]);  // left = min(f(l), f(u))
            out[BATCH + row] = f[2 * r + 1];                   // right = f(u)
        }
    }
}

extern "C" void kernel_launch(void* const* d_in, const int* in_sizes, int n_in,
                              void* d_out, int out_size, void* d_ws, size_t ws_size,
                              hipStream_t stream) {
    const float* x  = (const float*)d_in[0];   // (4096, 24)
    const float* ie = (const float*)d_in[1];   // (4094, 1)
    // d_in[2] = feature_matrix — provably unused (Mobius identity)
    float* out = (float*)d_out;                // left(4096) ++ right(4096)

    fused_kernel<<<NBLOCKS, THREADS, 0, stream>>>(x, ie, out);
}

// Round 6
// 19.191 us; speedup vs baseline: 4.2916x; 1.0362x over previous
//
#include <hip/hip_runtime.h>
#include <math.h>

#define NFEAT 12
#define NMASK 4095          // 2^12 - 1
#define BATCH 4096
#define THREADS 1024
#define ROWS_PER_BLOCK 16   // 16 waves x 1 row/wave
#define NBLOCKS (BATCH / ROWS_PER_BLOCK)   // 256

// ---------------------------------------------------------------------------
// Compile-time popcount-sorted permutation of masks 1..4095 (order within a
// level is irrelevant). Baked into the binary; L2-hot across all blocks.
// ---------------------------------------------------------------------------
struct Tables { unsigned short perm[4096]; };

constexpr int cpop(int x) { int c = 0; while (x) { c += x & 1; x >>= 1; } return c; }

constexpr Tables make_tables() {
    Tables t{};
    int cnt[13] = {};
    for (int m = 1; m <= NMASK; ++m) cnt[cpop(m)]++;
    int cur[13]; int acc = 0;
    for (int k = 0; k <= 12; ++k) { cur[k] = acc; acc += cnt[k]; }
    for (int m = 1; m <= NMASK; ++m) t.perm[cur[cpop(m)]++] = (unsigned short)m;
    t.perm[4095] = 0;
    return t;
}

constexpr Tables HOST_TBL = make_tables();
__device__ const Tables TBL = HOST_TBL;

// With 1024 threads every popcount level (2..11) is ONE slot: 10 slots.
#define NSLOT 10
__host__ __device__ constexpr int SLOT_OFF[NSLOT] =
    {12, 78, 298, 793, 1585, 2509, 3301, 3796, 4016, 4082};
__host__ __device__ constexpr int SLOT_CNT[NSLOT] =
    {66, 220, 495, 792, 924, 792, 495, 220, 66, 12};

__device__ __forceinline__ float bcast(float v, int t) {
#if __has_builtin(__builtin_amdgcn_readlane)
    return __int_as_float(__builtin_amdgcn_readlane(__float_as_int(v), t));
#else
    return __shfl(v, t, 64);
#endif
}

// ---------------------------------------------------------------------------
// Fused kernel: each block builds the FM table in its own 16 KB LDS via the
// lattice DP (one slot per level, 2-deep perm/ie prefetch pipeline), then
// evaluates 16 batch rows (1 row/wave):
//   f(y) = sum_A FM[A] * prod_{i in A} y_i * prod_{i notin A} (1-y_i)
//        = sum_l tlo[l] * ( sum_t thi[t] * min(g[t*64+l],1) )   (A=(t<<6)|l)
//   left = min(f(lo), f(hi)); right = f(hi).
// ---------------------------------------------------------------------------
__global__ __launch_bounds__(THREADS) void fused_kernel(const float* __restrict__ x,
                                                        const float* __restrict__ ie,
                                                        float* __restrict__ out) {
    __shared__ float g[4096];            // DP value by mask (g[0]=0, g[4095]=1)

    const int tid  = (int)threadIdx.x;
    const int lane = tid & 63;
    const int wave = tid >> 6;
    const int row  = (int)blockIdx.x * ROWS_PER_BLOCK + wave;   // 1 row per wave
    const unsigned short* __restrict__ P = TBL.perm;

    // ---- prologue: prefetch perm for slots 0,1 ----
    int mA = P[SLOT_OFF[0] + (tid < SLOT_CNT[0] ? tid : 0)];
    int mB = P[SLOT_OFF[1] + (tid < SLOT_CNT[1] ? tid : 0)];

    // seeds: level 1, full mask, empty mask
    if (tid < NFEAT)            g[1 << tid] = fabsf(ie[(1 << tid) - 1]);
    else if (tid == NFEAT)      g[NMASK] = 1.0f;
    else if (tid == NFEAT + 1)  g[0] = 0.0f;

    // per-lane row products for the wave's row (hides x-load latency)
    float tlo[2], thi[2], w[2];          // s=0: lower half, s=1: upper half
#pragma unroll
    for (int s = 0; s < 2; ++s) {
        const float* y = x + (size_t)row * (2 * NFEAT) + s * NFEAT;
        float a = 1.0f, b = 1.0f;
#pragma unroll
        for (int i = 0; i < 6; ++i) {
            const float yl = y[i], yh = y[6 + i];
            a *= ((lane >> i) & 1) ? yl : 1.0f - yl;
            b *= ((lane >> i) & 1) ? yh : 1.0f - yh;
        }
        tlo[s] = a; thi[s] = b; w[s] = 0.0f;
    }

    // ie value for slot 0 (dependent load; latency hidden by code above)
    float vaA = fabsf(ie[mA - 1]);

    __syncthreads();                     // seeds visible

    // ---- DP: 10 slots (one per level), 2-deep prefetch, barrier each ----
#pragma unroll
    for (int s = 0; s < NSLOT; ++s) {
        int mC = 0; float vaB = 0.0f;
        if (s + 2 < NSLOT) mC  = P[SLOT_OFF[s + 2] + (tid < SLOT_CNT[s + 2] ? tid : 0)];
        if (s + 1 < NSLOT) vaB = fabsf(ie[mB - 1]);   // perm arrived a slot ago
        if (tid < SLOT_CNT[s]) {
            const int m = mA;
            float best = -INFINITY;
#pragma unroll
            for (int i = 0; i < NFEAT; ++i) {
                const int has = (m >> i) & 1;
                const float c = g[m ^ (has << i)];    // child if bit set; 12 independent loads
                best = has ? fmaxf(best, c) : best;
            }
            g[m] = best + vaA;
        }
        __syncthreads();
        mA = mB; vaA = vaB; mB = mC;
    }

    // ---- eval: clamp fused into read; 1 ds_read + 2 readlane + 2 FMA per t ----
#pragma unroll
    for (int t = 0; t < 64; ++t) {
        const float fmv = fminf(g[t * 64 + lane], 1.0f);   // conflict-free
        w[0] = fmaf(bcast(thi[0], t), fmv, w[0]);
        w[1] = fmaf(bcast(thi[1], t), fmv, w[1]);
    }

    float f[2];
#pragma unroll
    for (int s = 0; s < 2; ++s) {
        float v = w[s] * tlo[s];
#pragma unroll
        for (int o = 32; o >= 1; o >>= 1)
            v += __shfl_xor(v, o, 64);
        f[s] = v;
    }

    if (lane == 0) {
        out[row]         = fminf(f[0], f[1]);   // left = min(f(lo), f(hi))
        out[BATCH + row] = f[1];                // right = f(hi)
    }
}

extern "C" void kernel_launch(void* const* d_in, const int* in_sizes, int n_in,
                              void* d_out, int out_size, void* d_ws, size_t ws_size,
                              hipStream_t stream) {
    const float* x  = (const float*)d_in[0];   // (4096, 24)
    const float* ie = (const float*)d_in[1];   // (4094, 1)
    // d_in[2] = feature_matrix — provably unused (Mobius identity)
    float* out = (float*)d_out;                // left(4096) ++ right(4096)

    fused_kernel<<<NBLOCKS, THREADS, 0, stream>>>(x, ie, out);
}

// Round 7
// 15.095 us; speedup vs baseline: 5.4562x; 1.2714x over previous
//
#include <hip/hip_runtime.h>
#include <math.h>

#define NFEAT 12
#define NMASK 4095          // 2^12 - 1
#define BATCH 4096
#define THREADS 512
#define ROWS_PER_BLOCK 8    // 8 waves x 1 row/wave
#define NBLOCKS (BATCH / ROWS_PER_BLOCK)   // 512 -> 2 blocks/CU (2 barrier domains)

// ---------------------------------------------------------------------------
// Compile-time popcount-sorted permutation of masks 1..4095 (order within a
// level is irrelevant). Baked into the binary; L2-hot across all blocks.
// ---------------------------------------------------------------------------
struct Tables { unsigned short perm[4096]; };

constexpr int cpop(int x) { int c = 0; while (x) { c += x & 1; x >>= 1; } return c; }

constexpr Tables make_tables() {
    Tables t{};
    int cnt[13] = {};
    for (int m = 1; m <= NMASK; ++m) cnt[cpop(m)]++;
    int cur[13]; int acc = 0;
    for (int k = 0; k <= 12; ++k) { cur[k] = acc; acc += cnt[k]; }
    for (int m = 1; m <= NMASK; ++m) t.perm[cur[cpop(m)]++] = (unsigned short)m;
    t.perm[4095] = 0;
    return t;
}

constexpr Tables HOST_TBL = make_tables();
__device__ const Tables TBL = HOST_TBL;

// 512-thread slot schedule: levels 2..11, sub-split where count > 512.
// Barrier only at level boundaries (sub-slots of one level are independent).
#define NSLOT 13
__host__ __device__ constexpr int SLOT_OFF[NSLOT] =
    {12, 78, 298, 793, 1305, 1585, 2097, 2509, 3021, 3301, 3796, 4016, 4082};
__host__ __device__ constexpr int SLOT_CNT[NSLOT] =
    {66, 220, 495, 512, 280, 512, 412, 512, 280, 495, 220, 66, 12};
__host__ __device__ constexpr int SLOT_K[NSLOT] =
    {2, 3, 4, 5, 5, 6, 6, 7, 7, 8, 9, 10, 11};
__host__ __device__ constexpr int SLOT_BAR[NSLOT] =
    {1, 1, 1, 0, 1, 0, 1, 0, 1, 1, 1, 1, 1};

__device__ __forceinline__ float bcast(float v, int t) {
#if __has_builtin(__builtin_amdgcn_readlane)
    return __int_as_float(__builtin_amdgcn_readlane(__float_as_int(v), t));
#else
    return __shfl(v, t, 64);
#endif
}

// ---------------------------------------------------------------------------
// Fused kernel: each block builds the FM table in its own 16 KB LDS via the
// lattice DP (all perm/ie preloaded to registers in one prologue burst;
// exactly-k child loads per mask), then evaluates 8 batch rows (1 row/wave):
//   f(y) = sum_A FM[A] * prod_{i in A} y_i * prod_{i notin A} (1-y_i)
//        = sum_l tlo[l] * ( sum_t thi[t] * min(g[t*64+l],1) )   (A=(t<<6)|l)
//   left = min(f(lo), f(hi)); right = f(hi).
// Two blocks co-resident per CU: independent barrier domains overlap each
// other's level-barrier stalls.
// ---------------------------------------------------------------------------
__global__ __launch_bounds__(THREADS) void fused_kernel(const float* __restrict__ x,
                                                        const float* __restrict__ ie,
                                                        float* __restrict__ out) {
    __shared__ float g[4096];            // DP value by mask (g[0]=0, g[4095]=1)

    const int tid  = (int)threadIdx.x;
    const int lane = tid & 63;
    const int wave = tid >> 6;
    const int row  = (int)blockIdx.x * ROWS_PER_BLOCK + wave;   // 1 row per wave
    const unsigned short* __restrict__ P = TBL.perm;

    // ---- prologue: ALL perm loads (independent), then ALL ie loads ----
    int   pm[NSLOT];
    float pv[NSLOT];
#pragma unroll
    for (int s = 0; s < NSLOT; ++s)
        pm[s] = P[SLOT_OFF[s] + (tid < SLOT_CNT[s] ? tid : 0)];
#pragma unroll
    for (int s = 0; s < NSLOT; ++s)
        pv[s] = fabsf(ie[pm[s] - 1]);

    // seeds: level 1, full mask, empty mask
    if (tid < NFEAT)            g[1 << tid] = fabsf(ie[(1 << tid) - 1]);
    else if (tid == NFEAT)      g[NMASK] = 1.0f;
    else if (tid == NFEAT + 1)  g[0] = 0.0f;

    // per-lane row products (overlap global latency with the preload burst)
    float tlo[2], thi[2], w[2];          // s=0: lower half, s=1: upper half
#pragma unroll
    for (int s = 0; s < 2; ++s) {
        const float* y = x + (size_t)row * (2 * NFEAT) + s * NFEAT;
        float a = 1.0f, b = 1.0f;
#pragma unroll
        for (int i = 0; i < 6; ++i) {
            const float yl = y[i], yh = y[6 + i];
            a *= ((lane >> i) & 1) ? yl : 1.0f - yl;
            b *= ((lane >> i) & 1) ? yh : 1.0f - yh;
        }
        tlo[s] = a; thi[s] = b; w[s] = 0.0f;
    }
    __syncthreads();                     // seeds visible

    // ---- DP: 13 slots, pure LDS/VALU (exactly-k child loads per mask) ----
#pragma unroll
    for (int s = 0; s < NSLOT; ++s) {
        if (tid < SLOT_CNT[s]) {
            const int m = pm[s];
            int mm = m;
            float best = -INFINITY;
#pragma unroll
            for (int j = 0; j < SLOT_K[s]; ++j) {    // compile-time k
                const int low = mm & (-mm);
                best = fmaxf(best, g[m ^ low]);      // load issues as low resolves
                mm ^= low;
            }
            g[m] = best + pv[s];
        }
        if (SLOT_BAR[s]) __syncthreads();
    }

    // ---- eval: clamp fused into read; 1 ds_read + 2 readlane + 2 FMA per t ----
#pragma unroll
    for (int t = 0; t < 64; ++t) {
        const float fmv = fminf(g[t * 64 + lane], 1.0f);   // conflict-free
        w[0] = fmaf(bcast(thi[0], t), fmv, w[0]);
        w[1] = fmaf(bcast(thi[1], t), fmv, w[1]);
    }

    float f[2];
#pragma unroll
    for (int s = 0; s < 2; ++s) {
        float v = w[s] * tlo[s];
#pragma unroll
        for (int o = 32; o >= 1; o >>= 1)
            v += __shfl_xor(v, o, 64);
        f[s] = v;
    }

    if (lane == 0) {
        out[row]         = fminf(f[0], f[1]);   // left = min(f(lo), f(hi))
        out[BATCH + row] = f[1];                // right = f(hi)
    }
}

extern "C" void kernel_launch(void* const* d_in, const int* in_sizes, int n_in,
                              void* d_out, int out_size, void* d_ws, size_t ws_size,
                              hipStream_t stream) {
    const float* x  = (const float*)d_in[0];   // (4096, 24)
    const float* ie = (const float*)d_in[1];   // (4094, 1)
    // d_in[2] = feature_matrix — provably unused (Mobius identity)
    float* out = (float*)d_out;                // left(4096) ++ right(4096)

    fused_kernel<<<NBLOCKS, THREADS, 0, stream>>>(x, ie, out);
}

// Round 8
// 14.786 us; speedup vs baseline: 5.5705x; 1.0209x over previous
//
#include <hip/hip_runtime.h>
#include <math.h>

#define NFEAT 12
#define NMASK 4095          // 2^12 - 1
#define BATCH 4096
#define THREADS 256
#define ROWS_PER_BLOCK 8    // 4 waves x 2 rows/wave
#define NBLOCKS (BATCH / ROWS_PER_BLOCK)   // 512 -> 2 blocks/CU (2 barrier domains)

// ---------------------------------------------------------------------------
// Compile-time popcount-sorted permutation of masks 1..4095 (order within a
// level is irrelevant). Baked into the binary; L2-hot across all blocks.
// ---------------------------------------------------------------------------
struct Tables { unsigned short perm[4096]; };

constexpr int cpop(int x) { int c = 0; while (x) { c += x & 1; x >>= 1; } return c; }

constexpr Tables make_tables() {
    Tables t{};
    int cnt[13] = {};
    for (int m = 1; m <= NMASK; ++m) cnt[cpop(m)]++;
    int cur[13]; int acc = 0;
    for (int k = 0; k <= 12; ++k) { cur[k] = acc; acc += cnt[k]; }
    for (int m = 1; m <= NMASK; ++m) t.perm[cur[cpop(m)]++] = (unsigned short)m;
    t.perm[4095] = 0;
    return t;
}

constexpr Tables HOST_TBL = make_tables();
__device__ const Tables TBL = HOST_TBL;

// 256-thread slot schedule: levels 2..11 sub-split into <=256-thread slots.
// Barrier only at level boundaries (sub-slots of one level are independent).
#define NSLOT 21
__host__ __device__ constexpr int SLOT_OFF[NSLOT] = {
    12, 78, 298, 554, 793, 1049, 1305, 1561, 1585, 1841, 2097,
    2353, 2509, 2765, 3021, 3277, 3301, 3557, 3796, 4016, 4082};
__host__ __device__ constexpr int SLOT_CNT[NSLOT] = {
    66, 220, 256, 239, 256, 256, 256, 24, 256, 256, 256,
    156, 256, 256, 256, 24, 256, 239, 220, 66, 12};
__host__ __device__ constexpr int SLOT_K[NSLOT] = {
    2, 3, 4, 4, 5, 5, 5, 5, 6, 6, 6,
    6, 7, 7, 7, 7, 8, 8, 9, 10, 11};
__host__ __device__ constexpr int SLOT_BAR[NSLOT] = {
    1, 1, 0, 1, 0, 0, 0, 1, 0, 0, 0,
    1, 0, 0, 0, 1, 0, 1, 1, 1, 1};

__device__ __forceinline__ float bcast(float v, int t) {
#if __has_builtin(__builtin_amdgcn_readlane)
    return __int_as_float(__builtin_amdgcn_readlane(__float_as_int(v), t));
#else
    return __shfl(v, t, 64);
#endif
}

// ---------------------------------------------------------------------------
// Fused kernel: each block builds the FM table in its own 16 KB LDS via the
// lattice DP (all perm/ie preloaded to registers in one prologue burst;
// exactly-k child loads per mask), then evaluates 8 rows (2 rows/wave, so
// each eval ds_read feeds 4 FMAs):
//   f(y) = sum_A FM[A] * prod_{i in A} y_i * prod_{i notin A} (1-y_i)
//        = sum_l tlo[l] * ( sum_t thi[t] * min(g[t*64+l],1) )   (A=(t<<6)|l)
//   left = min(f(lo), f(hi)); right = f(hi).
// Two blocks co-resident per CU: independent barrier domains overlap each
// other's level-barrier stalls.
// ---------------------------------------------------------------------------
__global__ __launch_bounds__(THREADS) void fused_kernel(const float* __restrict__ x,
                                                        const float* __restrict__ ie,
                                                        float* __restrict__ out) {
    __shared__ float g[4096];            // DP value by mask (g[0]=0, g[4095]=1)

    const int tid  = (int)threadIdx.x;
    const int lane = tid & 63;
    const int wave = tid >> 6;
    const int row0 = (int)blockIdx.x * ROWS_PER_BLOCK + wave * 2;  // 2 rows/wave
    const unsigned short* __restrict__ P = TBL.perm;

    // ---- prologue: ALL perm loads (independent), then ALL ie loads ----
    int   pm[NSLOT];
    float pv[NSLOT];
#pragma unroll
    for (int s = 0; s < NSLOT; ++s)
        pm[s] = P[SLOT_OFF[s] + (tid < SLOT_CNT[s] ? tid : 0)];
#pragma unroll
    for (int s = 0; s < NSLOT; ++s)
        pv[s] = fabsf(ie[pm[s] - 1]);

    // seeds: level 1, full mask, empty mask
    if (tid < NFEAT)            g[1 << tid] = fabsf(ie[(1 << tid) - 1]);
    else if (tid == NFEAT)      g[NMASK] = 1.0f;
    else if (tid == NFEAT + 1)  g[0] = 0.0f;

    // per-lane row products (overlap global latency with the preload burst)
    float tlo[4], thi[4], w[4];          // e = r*2 + s (r=row, s=0 lo / 1 hi)
#pragma unroll
    for (int e = 0; e < 4; ++e) {
        const int r = e >> 1, s = e & 1;
        const float* y = x + (size_t)(row0 + r) * (2 * NFEAT) + s * NFEAT;
        float a = 1.0f, b = 1.0f;
#pragma unroll
        for (int i = 0; i < 6; ++i) {
            const float yl = y[i], yh = y[6 + i];
            a *= ((lane >> i) & 1) ? yl : 1.0f - yl;
            b *= ((lane >> i) & 1) ? yh : 1.0f - yh;
        }
        tlo[e] = a; thi[e] = b; w[e] = 0.0f;
    }
    __syncthreads();                     // seeds visible

    // ---- DP: 21 slots, pure LDS/VALU (exactly-k child loads per mask) ----
#pragma unroll
    for (int s = 0; s < NSLOT; ++s) {
        if (tid < SLOT_CNT[s]) {
            const int m = pm[s];
            int mm = m;
            float best = -INFINITY;
#pragma unroll
            for (int j = 0; j < SLOT_K[s]; ++j) {    // compile-time k
                const int low = mm & (-mm);
                best = fmaxf(best, g[m ^ low]);      // independent LDS gathers
                mm ^= low;
            }
            g[m] = best + pv[s];
        }
        if (SLOT_BAR[s]) __syncthreads();
    }

    // ---- eval: clamp fused into read; 1 ds_read + 4 readlane + 4 FMA per t ----
#pragma unroll
    for (int t = 0; t < 64; ++t) {
        const float fmv = fminf(g[t * 64 + lane], 1.0f);   // conflict-free
#pragma unroll
        for (int e = 0; e < 4; ++e)
            w[e] = fmaf(bcast(thi[e], t), fmv, w[e]);
    }

    float f[4];
#pragma unroll
    for (int e = 0; e < 4; ++e) {
        float v = w[e] * tlo[e];
#pragma unroll
        for (int o = 32; o >= 1; o >>= 1)
            v += __shfl_xor(v, o, 64);
        f[e] = v;
    }

    if (lane == 0) {
#pragma unroll
        for (int r = 0; r < 2; ++r) {
            const int row = row0 + r;
            out[row]         = fminf(f[2 * r], f[2 * r + 1]);  // left = min(f(lo), f(hi))
            out[BATCH + row] = f[2 * r + 1];                   // right = f(hi)
        }
    }
}

extern "C" void kernel_launch(void* const* d_in, const int* in_sizes, int n_in,
                              void* d_out, int out_size, void* d_ws, size_t ws_size,
                              hipStream_t stream) {
    const float* x  = (const float*)d_in[0];   // (4096, 24)
    const float* ie = (const float*)d_in[1];   // (4094, 1)
    // d_in[2] = feature_matrix — provably unused (Mobius identity)
    float* out = (float*)d_out;                // left(4096) ++ right(4096)

    fused_kernel<<<NBLOCKS, THREADS, 0, stream>>>(x, ie, out);
}